// Round 3
// baseline (454.332 us; speedup 1.0000x reference)
//
#include <hip/hip_runtime.h>

typedef __attribute__((ext_vector_type(8))) short short8;
typedef __attribute__((ext_vector_type(4))) float float4v;

#define NSAMP 10000

// fp32 -> bf16 bits, round-to-nearest-even (finite inputs)
static __device__ __forceinline__ ushort f2bf(float v) {
    unsigned int x = __float_as_uint(v);
    return (ushort)((x + 0x7fffu + ((x >> 16) & 1u)) >> 16);
}

// Pre-permute + downconvert weights: Wa[co][kk], kk = k*64 + ci (bf16 bits).
// src: float w[co][ci][k] (strides 192, 3, 1)
__global__ void prep_weights(const float* __restrict__ w, ushort* __restrict__ wa) {
    int o = blockIdx.x * blockDim.x + threadIdx.x;
    if (o >= 128 * 192) return;
    int co = o / 192;
    int kk = o - co * 192;
    int k  = kk >> 6;
    int ci = kk & 63;
    wa[o] = f2bf(w[co * 192 + ci * 3 + k]);
}

// One sample per block, 4 waves. Wave w owns ALL 128 co (8 M-tiles, GLU pairs
// in-wave) for t in [16w, 16w+16). x staged in LDS as bf16 [ci][t] rows padded
// to 66 (ds_read_u16 banks = (cib+j + t/2)%32 -> 2 lanes/bank = conflict-free).
__global__ __launch_bounds__(256, 4)
void conv_glu(const float* __restrict__ x, const ushort* __restrict__ wa,
              const float* __restrict__ bias, float* __restrict__ out) {
    __shared__ uint xt32[64 * 33];                 // 64 rows x 66 ushort (8448 B)
    const ushort* xt = (const ushort*)xt32;

    const int n   = blockIdx.x;
    const int tid = threadIdx.x;
    const int w   = tid >> 6;      // wave id 0..3 -> t-quarter
    const int L   = tid & 63;
    const int l   = L & 15;
    const int q   = L >> 4;

    // ---- stage sample: 4096 floats, coalesced float4, cvt to bf16, to LDS ----
    const float4v* xg = (const float4v*)(x + n * 4096);
#pragma unroll
    for (int it = 0; it < 4; ++it) {
        int ci = (tid >> 4) + 16 * it;
        int tt = tid & 15;                         // covers t = 4*tt .. 4*tt+3
        float4v v = xg[ci * 16 + tt];
        xt32[ci * 33 + tt * 2]     = (uint)f2bf(v.x) | ((uint)f2bf(v.y) << 16);
        xt32[ci * 33 + tt * 2 + 1] = (uint)f2bf(v.z) | ((uint)f2bf(v.w) << 16);
    }
    __syncthreads();

    float4v acc[8];
#pragma unroll
    for (int mt = 0; mt < 8; ++mt) acc[mt] = (float4v){0.f, 0.f, 0.f, 0.f};

    const int t0 = 16 * w;

    // K loop: chunk kc covers conv-tap k = kc>>1, ci base = (kc&1)*32 + q*8.
    // B layout: B[k=q*8+j][n=l] = xbf[ci=cib+j][t = t0+l + (kc>>1)].
    // A layout: A[m=l][k=q*8+j] = wa[co=mt*16+l][kk=kc*32+q*8+j] (16B L2-hot).
#pragma unroll
    for (int kc = 0; kc < 6; ++kc) {
        const int cib = (kc & 1) * 32 + q * 8;
        int t = t0 + l + (kc >> 1);
        if (t > 63) t = 63;                        // pad cols, results discarded
        short8 bfr;
#pragma unroll
        for (int j = 0; j < 8; ++j)
            bfr[j] = (short)xt[(cib + j) * 66 + t];
#pragma unroll
        for (int mt = 0; mt < 8; ++mt) {
            short8 afr = *(const short8*)(wa + (mt * 16 + l) * 192 + kc * 32 + q * 8);
            acc[mt] = __builtin_amdgcn_mfma_f32_16x16x32_bf16(afr, bfr, acc[mt], 0, 0, 0);
        }
    }

    // ---- epilogue: bias + GLU (value mt=p2, gate mt=p2+4), fp32 store ----
    // D layout: row = q*4 + r (co within tile), col = l (t offset).
    const int t = t0 + l;
#pragma unroll
    for (int p2 = 0; p2 < 4; ++p2) {
#pragma unroll
        for (int r = 0; r < 4; ++r) {
            int co = p2 * 16 + q * 4 + r;
            float a = acc[p2][r]     + bias[co];
            float g = acc[p2 + 4][r] + bias[co + 64];
            float sg = 1.0f / (1.0f + __expf(-g));
            if (t < 62)
                out[(n * 64 + co) * 62 + t] = a * sg;
        }
    }
}

extern "C" void kernel_launch(void* const* d_in, const int* in_sizes, int n_in,
                              void* d_out, int out_size, void* d_ws, size_t ws_size,
                              hipStream_t stream) {
    const float* x    = (const float*)d_in[0];
    const float* wt   = (const float*)d_in[1];
    const float* bias = (const float*)d_in[2];
    ushort*      wa   = (ushort*)d_ws;            // 48 KB permuted bf16 weights
    float*       out  = (float*)d_out;

    prep_weights<<<96, 256, 0, stream>>>(wt, wa);
    conv_glu<<<NSAMP, 256, 0, stream>>>(x, wa, bias, out);
}